// Round 3
// baseline (311.932 us; speedup 1.0000x reference)
//
#include <hip/hip_runtime.h>

#define W 1024
#define H 1024
#define NB 16
#define TX 64   // output tile width
#define TY 16   // output tile height
#define VC 72   // vbuf cols = TX + 8 (halo 3 left, 3 right, +2 align pad); col v <-> global x = x0-4+v
#define NCG 18  // VC/4 column groups in vertical stage
#define NTASK (TY * NCG)  // 288 vertical-conv tasks per block

// Fused SSIM: vertical separable conv from global (coalesced, L1-reused) into an
// 8-channel LDS buffer, then horizontal conv + SSIM map + block reduction.
// LDS = 36 KB -> 4 blocks/CU.
__global__ __launch_bounds__(256) void ssim_main(
    const float* __restrict__ img1, const float* __restrict__ img2,
    const float* __restrict__ img3, const float* __restrict__ win,
    float* __restrict__ partial)
{
    __shared__ __align__(16) float vbuf[8][TY][VC];  // 36864 B

    const int tid = threadIdx.x;
    const int b  = blockIdx.z;
    const int x0 = blockIdx.x * TX;
    const int y0 = blockIdx.y * TY;
    const size_t imoff = (size_t)b * (size_t)(W * H);
    const float* p1 = img1 + imoff;
    const float* p2 = img2 + imoff;
    const float* p3 = img3 + imoff;

    // Separable 1-D gaussian from the 2-D window: g[j] = win[3][j] / sqrt(win[3][3])
    float g[7];
    {
        const float g3 = sqrtf(win[24]);
        #pragma unroll
        for (int j = 0; j < 7; ++j) g[j] = win[21 + j] / g3;
    }

    const bool interior = (blockIdx.x > 0) & (blockIdx.x < gridDim.x - 1) &
                          (blockIdx.y > 0) & (blockIdx.y < gridDim.y - 1);

    // ---- Stage V: vertical conv of the 8 product channels, global -> LDS ----
    for (int i = tid; i < NTASK; i += 256) {
        const int r  = i / NCG;
        const int cg = i - r * NCG;
        const int vc = cg << 2;          // vbuf col base
        const int gx = x0 - 4 + vc;      // global x of lane's 4 columns
        const int gy0 = y0 + r - 3;      // first of 7 input rows

        float a[8][4];
        #pragma unroll
        for (int ch = 0; ch < 8; ++ch)
            #pragma unroll
            for (int c = 0; c < 4; ++c) a[ch][c] = 0.0f;

        if (interior) {
            const float* q1 = p1 + (size_t)gy0 * W + gx;
            const float* q2 = p2 + (size_t)gy0 * W + gx;
            const float* q3 = p3 + (size_t)gy0 * W + gx;
            // depth-2 pipelined loads to bound VGPR while hiding L1 latency
            float4 n1 = *(const float4*)q1;
            float4 n2 = *(const float4*)q2;
            float4 n3 = *(const float4*)q3;
            #pragma unroll
            for (int dy = 0; dy < 7; ++dy) {
                const float4 c1 = n1, c2 = n2, c3 = n3;
                if (dy < 6) {
                    n1 = *(const float4*)(q1 + (dy + 1) * W);
                    n2 = *(const float4*)(q2 + (dy + 1) * W);
                    n3 = *(const float4*)(q3 + (dy + 1) * W);
                }
                const float wg = g[dy];
                const float x1[4] = {c1.x, c1.y, c1.z, c1.w};
                const float x2[4] = {c2.x, c2.y, c2.z, c2.w};
                const float x3[4] = {c3.x, c3.y, c3.z, c3.w};
                #pragma unroll
                for (int c = 0; c < 4; ++c) {
                    const float t1 = wg * x1[c];
                    const float t2 = wg * x2[c];
                    const float t3 = wg * x3[c];
                    a[0][c] += t1;
                    a[1][c] += t2;
                    a[2][c] += t3;
                    a[3][c] += t1 * x1[c];
                    a[4][c] += t2 * x2[c];
                    a[5][c] += t3 * x3[c];
                    a[6][c] += t1 * x2[c];
                    a[7][c] += t1 * x3[c];
                }
            }
        } else {
            #pragma unroll
            for (int dy = 0; dy < 7; ++dy) {
                const int y = gy0 + dy;
                const bool yok = (y >= 0) & (y < H);
                const float wg = g[dy];
                float x1[4], x2[4], x3[4];
                #pragma unroll
                for (int c = 0; c < 4; ++c) {
                    const int x = gx + c;
                    const bool ok = yok & (x >= 0) & (x < W);
                    const size_t off = (size_t)y * W + x;
                    x1[c] = ok ? p1[off] : 0.0f;
                    x2[c] = ok ? p2[off] : 0.0f;
                    x3[c] = ok ? p3[off] : 0.0f;
                }
                #pragma unroll
                for (int c = 0; c < 4; ++c) {
                    const float t1 = wg * x1[c];
                    const float t2 = wg * x2[c];
                    const float t3 = wg * x3[c];
                    a[0][c] += t1;
                    a[1][c] += t2;
                    a[2][c] += t3;
                    a[3][c] += t1 * x1[c];
                    a[4][c] += t2 * x2[c];
                    a[5][c] += t3 * x3[c];
                    a[6][c] += t1 * x2[c];
                    a[7][c] += t1 * x3[c];
                }
            }
        }
        #pragma unroll
        for (int ch = 0; ch < 8; ++ch)
            *(float4*)&vbuf[ch][r][vc] = make_float4(a[ch][0], a[ch][1], a[ch][2], a[ch][3]);
    }
    __syncthreads();

    // ---- Stage H: horizontal conv (aligned b128 superset reads) + SSIM ----
    const int c0 = (tid & 15) << 2;  // output col group within tile
    const int r  = tid >> 4;         // output row within tile

    float s[8][4];
    #pragma unroll
    for (int ch = 0; ch < 8; ++ch) {
        float vv[12];
        *(float4*)&vv[0] = *(const float4*)&vbuf[ch][r][c0];
        *(float4*)&vv[4] = *(const float4*)&vbuf[ch][r][c0 + 4];
        *(float4*)&vv[8] = *(const float4*)&vbuf[ch][r][c0 + 8];
        #pragma unroll
        for (int j = 0; j < 4; ++j) {
            float t = 0.0f;
            #pragma unroll
            for (int dx = 0; dx < 7; ++dx) t += g[dx] * vv[1 + j + dx];
            s[ch][j] = t;
        }
    }

    float lsum = 0.0f;
    #pragma unroll
    for (int j = 0; j < 4; ++j) {
        const float mu1 = s[0][j], mu2 = s[1][j], mu3 = s[2][j];
        const float sig1  = s[3][j] - mu1 * mu1;
        const float sig2  = s[4][j] - mu2 * mu2;
        const float sig3  = s[5][j] - mu3 * mu3;
        const float sig12 = s[6][j] - mu1 * mu2;
        const float sig13 = s[7][j] - mu1 * mu3;
        const float C2 = 9.0e-4f;  // 0.03^2
        const float m12 = (2.0f * sig12 + C2) / (sig1 + sig2 + C2);
        const float m13 = (2.0f * sig13 + C2) / (sig1 + sig3 + C2);
        lsum += (mu2 > mu3) ? m12 : m13;
    }

    // ---- Block reduction (deterministic); reuse vbuf for the wave sums ----
    __syncthreads();  // all vbuf reads done before aliasing it
    #pragma unroll
    for (int o = 32; o > 0; o >>= 1) lsum += __shfl_down(lsum, o, 64);
    float* wsum = (float*)vbuf;
    if ((tid & 63) == 0) wsum[tid >> 6] = lsum;
    __syncthreads();
    if (tid == 0) {
        const float t = (wsum[0] + wsum[1]) + (wsum[2] + wsum[3]);
        partial[((size_t)blockIdx.z * gridDim.y + blockIdx.y) * gridDim.x + blockIdx.x] = t;
    }
}

// Deterministic final reduction: one block, fixed summation order, f64 accum.
__global__ __launch_bounds__(256) void ssim_reduce(
    const float* __restrict__ partial, float* __restrict__ out, int n)
{
    __shared__ double sh[256];
    const int tid = threadIdx.x;
    double s = 0.0;
    for (int i = tid; i < n; i += 256) s += (double)partial[i];
    sh[tid] = s;
    __syncthreads();
    for (int o = 128; o > 0; o >>= 1) {
        if (tid < o) sh[tid] += sh[tid + o];
        __syncthreads();
    }
    if (tid == 0) out[0] = (float)(sh[0] / (double)((size_t)NB * W * H));
}

extern "C" void kernel_launch(void* const* d_in, const int* in_sizes, int n_in,
                              void* d_out, int out_size, void* d_ws, size_t ws_size,
                              hipStream_t stream) {
    const float* img1 = (const float*)d_in[0];
    const float* img2 = (const float*)d_in[1];
    const float* img3 = (const float*)d_in[2];
    const float* win  = (const float*)d_in[3];
    float* out = (float*)d_out;
    float* partial = (float*)d_ws;

    dim3 grid(W / TX, H / TY, NB);
    ssim_main<<<grid, 256, 0, stream>>>(img1, img2, img3, win, partial);

    const int nblk = (W / TX) * (H / TY) * NB;
    ssim_reduce<<<1, 256, 0, stream>>>(partial, out, nblk);
}

// Round 4
// 163.950 us; speedup vs baseline: 1.9026x; 1.9026x over previous
//
#include <hip/hip_runtime.h>

#define W 1024
#define H 1024
#define NB 16
#define TX 32
#define TY 16
#define HR (TY + 6)      // 22 rows of h-conv results
#define NTB (HR * 8)     // 176 stage-B tasks (22 rows x 8 col-groups of 4)

// Fused SSIM, hbuf-only LDS version:
//   Stage B: horizontal 7-tap conv of the 8 product channels, reading the
//            3 images directly from global (3x aligned float4 per image),
//            writing b128 to LDS. Each input row h-convolved once per block.
//   Stage C: vertical 7-tap conv from LDS + SSIM map + block reduction.
// LDS = 22.5 KB -> 5-6 blocks/CU; launch_bounds caps VGPR for 5 waves/SIMD.
__global__ __launch_bounds__(256, 5) void ssim_main(
    const float* __restrict__ img1, const float* __restrict__ img2,
    const float* __restrict__ img3, const float* __restrict__ win,
    float* __restrict__ partial)
{
    __shared__ __align__(16) float hbuf[8][HR][TX];  // 22528 B
    __shared__ float wavesum[4];

    const int tid = threadIdx.x;
    const int x0 = blockIdx.x * TX;
    const int y0 = blockIdx.y * TY;
    const size_t imoff = (size_t)blockIdx.z * (size_t)(W * H);
    const float* p1 = img1 + imoff;
    const float* p2 = img2 + imoff;
    const float* p3 = img3 + imoff;

    // Separable 1-D gaussian from the 2-D window: g[j] = win[3][j] / sqrt(win[3][3])
    float g[7];
    {
        const float g3 = sqrtf(win[24]);
        #pragma unroll
        for (int j = 0; j < 7; ++j) g[j] = win[21 + j] / g3;
    }

    // ---- Stage B: horizontal conv, global -> LDS ----
    // Task i: h-conv row gy = y0 + r - 3 at output cols x0+c0 .. x0+c0+3.
    // Window cols x0+c0-3 .. x0+c0+6 live in V[1..10] of the 12-float
    // aligned superset starting at gx0 = x0+c0-4.
    for (int i = tid; i < NTB; i += 256) {
        const int r  = i >> 3;
        const int c0 = (i & 7) << 2;
        const int gy = y0 + r - 3;

        float acc[8][4];
        #pragma unroll
        for (int ch = 0; ch < 8; ++ch)
            #pragma unroll
            for (int j = 0; j < 4; ++j) acc[ch][j] = 0.0f;

        if ((gy >= 0) & (gy < H)) {
            const int gx0 = x0 + c0 - 4;
            const size_t rowoff = (size_t)gy * W;
            float V1[12], V2[12], V3[12];
            if ((gx0 >= 0) & (gx0 + 12 <= W)) {
                const float* q1 = p1 + rowoff + gx0;
                const float* q2 = p2 + rowoff + gx0;
                const float* q3 = p3 + rowoff + gx0;
                *(float4*)&V1[0] = *(const float4*)(q1);
                *(float4*)&V1[4] = *(const float4*)(q1 + 4);
                *(float4*)&V1[8] = *(const float4*)(q1 + 8);
                *(float4*)&V2[0] = *(const float4*)(q2);
                *(float4*)&V2[4] = *(const float4*)(q2 + 4);
                *(float4*)&V2[8] = *(const float4*)(q2 + 8);
                *(float4*)&V3[0] = *(const float4*)(q3);
                *(float4*)&V3[4] = *(const float4*)(q3 + 4);
                *(float4*)&V3[8] = *(const float4*)(q3 + 8);
            } else {
                #pragma unroll
                for (int c = 0; c < 12; ++c) {
                    const int x = gx0 + c;
                    const bool ok = (x >= 0) & (x < W);
                    const size_t off = rowoff + x;
                    V1[c] = ok ? p1[off] : 0.0f;
                    V2[c] = ok ? p2[off] : 0.0f;
                    V3[c] = ok ? p3[off] : 0.0f;
                }
            }
            #pragma unroll
            for (int j = 0; j < 4; ++j) {
                #pragma unroll
                for (int dx = 0; dx < 7; ++dx) {
                    const float wg = g[dx];
                    const float v1 = V1[1 + j + dx];
                    const float v2 = V2[1 + j + dx];
                    const float v3 = V3[1 + j + dx];
                    const float t1 = wg * v1;
                    const float t2 = wg * v2;
                    const float t3 = wg * v3;
                    acc[0][j] += t1;
                    acc[1][j] += t2;
                    acc[2][j] += t3;
                    acc[3][j] += t1 * v1;
                    acc[4][j] += t2 * v2;
                    acc[5][j] += t3 * v3;
                    acc[6][j] += t1 * v2;
                    acc[7][j] += t1 * v3;
                }
            }
        }
        #pragma unroll
        for (int ch = 0; ch < 8; ++ch)
            *(float4*)&hbuf[ch][r][c0] =
                make_float4(acc[ch][0], acc[ch][1], acc[ch][2], acc[ch][3]);
    }
    __syncthreads();

    // ---- Stage C: vertical conv (2-tall per thread, perfectly balanced) ----
    const int tx = tid & 31;
    const int k  = tid >> 5;          // 0..7 -> output rows 2k, 2k+1
    const int rb = k << 1;

    float s[8][2];
    #pragma unroll
    for (int ch = 0; ch < 8; ++ch) {
        const float* base = &hbuf[ch][rb][tx];
        float v[8];
        #pragma unroll
        for (int dy = 0; dy < 8; ++dy) v[dy] = base[dy * TX];
        float t0 = 0.0f, t1 = 0.0f;
        #pragma unroll
        for (int dy = 0; dy < 7; ++dy) {
            t0 += g[dy] * v[dy];
            t1 += g[dy] * v[dy + 1];
        }
        s[ch][0] = t0;
        s[ch][1] = t1;
    }

    float lsum = 0.0f;
    #pragma unroll
    for (int j = 0; j < 2; ++j) {
        const float mu1 = s[0][j], mu2 = s[1][j], mu3 = s[2][j];
        const float sig1  = s[3][j] - mu1 * mu1;
        const float sig2  = s[4][j] - mu2 * mu2;
        const float sig3  = s[5][j] - mu3 * mu3;
        const float sig12 = s[6][j] - mu1 * mu2;
        const float sig13 = s[7][j] - mu1 * mu3;
        const float C2 = 9.0e-4f;  // 0.03^2
        const float m12 = (2.0f * sig12 + C2) / (sig1 + sig2 + C2);
        const float m13 = (2.0f * sig13 + C2) / (sig1 + sig3 + C2);
        lsum += (mu2 > mu3) ? m12 : m13;
    }

    // ---- Block reduction (deterministic) ----
    #pragma unroll
    for (int o = 32; o > 0; o >>= 1) lsum += __shfl_down(lsum, o, 64);
    if ((tid & 63) == 0) wavesum[tid >> 6] = lsum;
    __syncthreads();
    if (tid == 0) {
        const float t = (wavesum[0] + wavesum[1]) + (wavesum[2] + wavesum[3]);
        partial[((size_t)blockIdx.z * gridDim.y + blockIdx.y) * gridDim.x + blockIdx.x] = t;
    }
}

// Deterministic final reduction: one block, fixed summation order, f64 accum.
__global__ __launch_bounds__(256) void ssim_reduce(
    const float* __restrict__ partial, float* __restrict__ out, int n)
{
    __shared__ double sh[256];
    const int tid = threadIdx.x;
    double s = 0.0;
    for (int i = tid; i < n; i += 256) s += (double)partial[i];
    sh[tid] = s;
    __syncthreads();
    for (int o = 128; o > 0; o >>= 1) {
        if (tid < o) sh[tid] += sh[tid + o];
        __syncthreads();
    }
    if (tid == 0) out[0] = (float)(sh[0] / (double)((size_t)NB * W * H));
}

extern "C" void kernel_launch(void* const* d_in, const int* in_sizes, int n_in,
                              void* d_out, int out_size, void* d_ws, size_t ws_size,
                              hipStream_t stream) {
    const float* img1 = (const float*)d_in[0];
    const float* img2 = (const float*)d_in[1];
    const float* img3 = (const float*)d_in[2];
    const float* win  = (const float*)d_in[3];
    float* out = (float*)d_out;
    float* partial = (float*)d_ws;

    dim3 grid(W / TX, H / TY, NB);  // 32 x 64 x 16 = 32768 blocks
    ssim_main<<<grid, 256, 0, stream>>>(img1, img2, img3, win, partial);

    const int nblk = (W / TX) * (H / TY) * NB;
    ssim_reduce<<<1, 256, 0, stream>>>(partial, out, nblk);
}